// Round 1
// baseline (275.273 us; speedup 1.0000x reference)
//
#include <hip/hip_runtime.h>
#include <stdint.h>

#define BH 32
#define LSEQ 4096
#define DDIM 128
#define BS 32
#define NBLK 128
#define CHUNKS 16
#define BLK_PER_CHUNK 8
#define STATE_SZ (DDIM*DDIM + DDIM)   // 16512 floats per (bh, chunk)

typedef __attribute__((ext_vector_type(8))) short bf16x8;
typedef __attribute__((ext_vector_type(4))) float f32x4;

__device__ inline uint16_t f2bf(float f) {
    uint32_t x = __builtin_bit_cast(uint32_t, f);
    x += 0x7fffu + ((x >> 16) & 1u);
    return (uint16_t)(x >> 16);
}
__device__ inline float bflo(uint32_t w){ return __builtin_bit_cast(float, w << 16); }
__device__ inline float bfhi(uint32_t w){ return __builtin_bit_cast(float, w & 0xffff0000u); }

// phi(x) = clip(elu(x*s+b)+1, 0, 10) = (y>0) ? min(y+1,10) : exp(y)
__device__ inline float phi_f(float x, float s, float b) {
    float y = fmaf(x, s, b);
    float pos = fminf(y + 1.0f, 10.0f);
    float neg = __expf(y);
    return (y > 0.0f) ? pos : neg;
}

// Barrier with LDS-only drain: keeps register-prefetch global loads in flight
// across the barrier (no cross-wave communication through global memory
// inside the kernel, so skipping the vmcnt drain is safe).
__device__ inline void bar_lgkm() {
    asm volatile("s_waitcnt lgkmcnt(0)\n\ts_barrier" ::: "memory");
}

// LDS byte map (57984 B total):
//   [0,10240)       : pkT [128][40] bf16 ; pq_bf [32][136] overlays @0 (phase2, after S-MFMAs)
//   [10240,20480)   : vT  [128][40] bf16
//   [20480,55296)   : S_bfT [128][136] bf16 (phase2 only)
//   [55296,55808)   : Zl   [128] f32
//   [55808,57856)   : Zpart[4][128] f32
//   [57856,57984)   : inv_den [32] f32
#define SMEM_BYTES 57984

template<bool PHASE2>
__global__ __launch_bounds__(512, 4) void la_phase(
    const float* __restrict__ Q, const float* __restrict__ K,
    const float* __restrict__ V, const float* __restrict__ scale,
    const float* __restrict__ bias, float* __restrict__ states,
    float* __restrict__ out)
{
    extern __shared__ char smem[];
    uint16_t* pkT    = (uint16_t*)smem;
    uint16_t* pq_bf  = (uint16_t*)smem;
    uint16_t* vT     = (uint16_t*)(smem + 10240);
    uint16_t* S_bfT  = (uint16_t*)(smem + 20480);
    float* Zl        = (float*)(smem + 55296);
    float* Zpart     = Zl + 128;
    float* inv_den   = Zpart + 4*128;

    const int tid  = threadIdx.x;
    const int bid  = blockIdx.x;
    const int bh   = bid >> 4;        // / CHUNKS
    const int ch   = bid & 15;
    const int lane = tid & 63;
    const int wv   = tid >> 6;        // wave 0..7, owns e in [16wv,16wv+16)
    const int i15  = lane & 15;
    const int q4   = lane >> 4;

    const size_t base = (size_t)bh * LSEQ * DDIM;
    const int h = bh & 15;

    // K/V staging assignment: one column d per thread, 8 rows r=8*rg..8*rg+7
    const int kd = tid & 127;
    const int rg = tid >> 7;          // 0..3
    // Q staging assignment (phase2): row sr, cols [sc, sc+8)
    const int sr = tid >> 4;
    const int sc = (tid & 15) * 8;

    const float sk = scale[h*DDIM + kd];
    const float bk = bias [h*DDIM + kd];
    float sreg[8], breg[8];
    if (PHASE2) {
        #pragma unroll
        for (int j = 0; j < 8; ++j) {
            sreg[j] = scale[h*DDIM + sc + j];
            breg[j] = bias [h*DDIM + sc + j];
        }
    }

    f32x4 accS[8];
    float* stbase = states + (size_t)(bh*CHUNKS + ch) * STATE_SZ;

    if (PHASE2) {
        #pragma unroll
        for (int mt = 0; mt < 8; ++mt) {
            #pragma unroll
            for (int r = 0; r < 4; ++r) {
                int d = 16*mt + 4*q4 + r;
                accS[mt][r] = stbase[d*DDIM + 16*wv + i15];
            }
        }
        if (tid < 128) Zl[tid] = stbase[DDIM*DDIM + tid];
    } else {
        #pragma unroll
        for (int mt = 0; mt < 8; ++mt) accS[mt] = (f32x4){0.f,0.f,0.f,0.f};
        if (tid < 128) Zl[tid] = 0.f;
    }
    __syncthreads();

    // ---- register prefetch for s = 0
    float kreg[8], vreg[8], qreg[8];
    {
        const size_t coff = base + (size_t)((ch*BLK_PER_CHUNK)*BS + 8*rg)*DDIM + kd;
        #pragma unroll
        for (int j = 0; j < 8; ++j) {
            kreg[j] = K[coff + (size_t)j*DDIM];
            vreg[j] = V[coff + (size_t)j*DDIM];
        }
        if (PHASE2) {
            const size_t qoff = base + (size_t)((ch*BLK_PER_CHUNK)*BS + sr)*DDIM + sc;
            const float4 a0 = *(const float4*)(Q + qoff);
            const float4 a1 = *(const float4*)(Q + qoff + 4);
            qreg[0]=a0.x; qreg[1]=a0.y; qreg[2]=a0.z; qreg[3]=a0.w;
            qreg[4]=a1.x; qreg[5]=a1.y; qreg[6]=a1.z; qreg[7]=a1.w;
        }
    }

    for (int s = 0; s < BLK_PER_CHUNK; ++s) {
        const int blk = ch * BLK_PER_CHUNK + s;

        // ---- 1. stage phi(K) / bf16(V) DIRECTLY TRANSPOSED (b128 writes, bank-balanced)
        {
            uint32_t pk[4], pv[4];
            float zp = 0.f;
            #pragma unroll
            for (int j = 0; j < 4; ++j) {
                uint32_t lo = f2bf(phi_f(kreg[2*j],   sk, bk));
                uint32_t hi = f2bf(phi_f(kreg[2*j+1], sk, bk));
                pk[j] = lo | (hi << 16);
                zp += bflo(lo) + bflo(hi);
                uint32_t vlo = f2bf(vreg[2*j]);
                uint32_t vhi = f2bf(vreg[2*j+1]);
                pv[j] = vlo | (vhi << 16);
            }
            *(uint4*)&pkT[kd*40 + 8*rg] = *(uint4*)pk;
            *(uint4*)&vT [kd*40 + 8*rg] = *(uint4*)pv;
            Zpart[rg*128 + kd] = zp;
        }
        // ---- prefetch next block's K/V into registers (in flight across barriers)
        if (s + 1 < BLK_PER_CHUNK) {
            const size_t coff = base + (size_t)((blk+1)*BS + 8*rg)*DDIM + kd;
            #pragma unroll
            for (int j = 0; j < 8; ++j) {
                kreg[j] = K[coff + (size_t)j*DDIM];
                vreg[j] = V[coff + (size_t)j*DDIM];
            }
        }
        bar_lgkm();   // B1: staging visible

        // ---- 2. Z update + S-update MFMAs (S[d][e] += sum_r pk[r][d] v[r][e])
        if (tid < 128) {
            float z = Zl[tid];
            #pragma unroll
            for (int g = 0; g < 4; ++g) z += Zpart[g*128 + tid];
            Zl[tid] = z;
        }
        {
            bf16x8 bv = *(const bf16x8*)&vT[(16*wv + i15)*40 + 8*q4];
            __builtin_amdgcn_s_setprio(1);
            #pragma unroll
            for (int mt = 0; mt < 8; ++mt) {
                bf16x8 av = *(const bf16x8*)&pkT[(16*mt + i15)*40 + 8*q4];
                accS[mt] = __builtin_amdgcn_mfma_f32_16x16x32_bf16(av, bv, accS[mt], 0, 0, 0);
            }
            __builtin_amdgcn_s_setprio(0);
        }

        if (PHASE2) {
            bar_lgkm();   // B2: pkT/vT reads done -> pq_bf may overwrite; Zl final

            // ---- 3. stage phi(Q) from prefetched regs; den from registers + shuffle
            {
                uint32_t pq[4];
                #pragma unroll
                for (int j = 0; j < 4; ++j) {
                    uint32_t lo = f2bf(phi_f(qreg[2*j],   sreg[2*j],   breg[2*j]));
                    uint32_t hi = f2bf(phi_f(qreg[2*j+1], sreg[2*j+1], breg[2*j+1]));
                    pq[j] = lo | (hi << 16);
                }
                *(uint4*)&pq_bf[sr*136 + sc] = *(uint4*)pq;
                float sden = 0.f;
                #pragma unroll
                for (int j = 0; j < 4; ++j)
                    sden += bflo(pq[j]) * Zl[sc + 2*j] + bfhi(pq[j]) * Zl[sc + 2*j + 1];
                #pragma unroll
                for (int off = 1; off < 16; off <<= 1)
                    sden += __shfl_xor(sden, off, 64);
                if ((tid & 15) == 0) inv_den[sr] = 1.0f / fmaxf(sden, 1e-6f);
            }
            // ---- 4. emit S as bf16 (e-major) for num
            #pragma unroll
            for (int mt = 0; mt < 8; ++mt) {
                uint2 o;
                o.x = (uint32_t)f2bf(accS[mt][0]) | ((uint32_t)f2bf(accS[mt][1]) << 16);
                o.y = (uint32_t)f2bf(accS[mt][2]) | ((uint32_t)f2bf(accS[mt][3]) << 16);
                *(uint2*)&S_bfT[(16*wv + i15)*136 + 16*mt + 4*q4] = o;
            }
            // ---- prefetch next block's Q
            if (s + 1 < BLK_PER_CHUNK) {
                const size_t qoff = base + (size_t)((blk+1)*BS + sr)*DDIM + sc;
                const float4 a0 = *(const float4*)(Q + qoff);
                const float4 a1 = *(const float4*)(Q + qoff + 4);
                qreg[0]=a0.x; qreg[1]=a0.y; qreg[2]=a0.z; qreg[3]=a0.w;
                qreg[4]=a1.x; qreg[5]=a1.y; qreg[6]=a1.z; qreg[7]=a1.w;
            }
            bar_lgkm();   // B3: pq_bf, S_bfT, inv_den visible

            // ---- 5. num MFMAs
            f32x4 acc2[2];
            acc2[0] = (f32x4){0.f,0.f,0.f,0.f};
            acc2[1] = (f32x4){0.f,0.f,0.f,0.f};
            __builtin_amdgcn_s_setprio(1);
            #pragma unroll
            for (int ks = 0; ks < 4; ++ks) {
                bf16x8 sb = *(const bf16x8*)&S_bfT[(16*wv + i15)*136 + 32*ks + 8*q4];
                #pragma unroll
                for (int qt = 0; qt < 2; ++qt) {
                    bf16x8 qa = *(const bf16x8*)&pq_bf[(16*qt + i15)*136 + 32*ks + 8*q4];
                    acc2[qt] = __builtin_amdgcn_mfma_f32_16x16x32_bf16(qa, sb, acc2[qt], 0, 0, 0);
                }
            }
            __builtin_amdgcn_s_setprio(0);
            bar_lgkm();   // B4: pq_bf reads done -> next stage may overwrite

            // ---- 6. out = num * inv_den
            #pragma unroll
            for (int qt = 0; qt < 2; ++qt) {
                #pragma unroll
                for (int r = 0; r < 4; ++r) {
                    int qrow = 16*qt + 4*q4 + r;
                    float o = acc2[qt][r] * inv_den[qrow];
                    out[base + (size_t)(blk*BS + qrow)*DDIM + 16*wv + i15] = o;
                }
            }
        } else {
            bar_lgkm();   // B2: pkT/vT reads done -> next stage may overwrite
        }
    }

    if (!PHASE2) {
        #pragma unroll
        for (int mt = 0; mt < 8; ++mt) {
            #pragma unroll
            for (int r = 0; r < 4; ++r) {
                int d = 16*mt + 4*q4 + r;
                stbase[d*DDIM + 16*wv + i15] = accS[mt][r];
            }
        }
        if (tid < 128) stbase[DDIM*DDIM + tid] = Zl[tid];
    }
}

// In-place exclusive prefix over chunk states, per chain. grid 32*16, block 256.
__global__ void la_prefix(float* __restrict__ states) {
    const int bh = blockIdx.x >> 4;
    const int sl = blockIdx.x & 15;
    const int slice = STATE_SZ / 16;  // 1032
    float* p0 = states + (size_t)bh * CHUNKS * STATE_SZ + sl * slice;
    for (int i = threadIdx.x; i < slice; i += 256) {
        float run = 0.f;
        float* p = p0 + i;
        #pragma unroll
        for (int c = 0; c < CHUNKS; ++c) {
            float v = p[(size_t)c * STATE_SZ];
            p[(size_t)c * STATE_SZ] = run;
            run += v;
        }
    }
}

extern "C" void kernel_launch(void* const* d_in, const int* in_sizes, int n_in,
                              void* d_out, int out_size, void* d_ws, size_t ws_size,
                              hipStream_t stream) {
    const float* Q     = (const float*)d_in[0];
    const float* K     = (const float*)d_in[1];
    const float* V     = (const float*)d_in[2];
    const float* scale = (const float*)d_in[3];
    const float* bias  = (const float*)d_in[4];
    float* out    = (float*)d_out;
    float* states = (float*)d_ws;   // needs 32*16*16512*4 = 33.8 MB

    hipLaunchKernelGGL((la_phase<false>), dim3(BH*CHUNKS), dim3(512), SMEM_BYTES, stream,
                       Q, K, V, scale, bias, states, out);
    hipLaunchKernelGGL(la_prefix, dim3(BH*16), dim3(256), 0, stream, states);
    hipLaunchKernelGGL((la_phase<true>), dim3(BH*CHUNKS), dim3(512), SMEM_BYTES, stream,
                       Q, K, V, scale, bias, states, out);
}